// Round 3
// baseline (300.040 us; speedup 1.0000x reference)
//
#include <hip/hip_runtime.h>
#include <hip/hip_bf16.h>

#define BB 4
#define SS 1024
#define DD 1024
#define HH 16

typedef __attribute__((ext_vector_type(8))) short bf16x8;
typedef __attribute__((ext_vector_type(4))) float f32x4;
typedef unsigned int u32;
typedef unsigned long long u64;

__device__ __forceinline__ ushort f2bf(float f) {
    u32 u = __builtin_bit_cast(u32, f);
    u32 r = (u + 0x7fffu + ((u >> 16) & 1u)) >> 16;
    return (ushort)r;
}
__device__ __forceinline__ float bf2f(ushort h) {
    return __builtin_bit_cast(float, (u32)h << 16);
}

__device__ __forceinline__ void gload16(const ushort* g, ushort* l) {
    __builtin_amdgcn_global_load_lds(
        (const __attribute__((address_space(1))) u32*)(const void*)g,
        (__attribute__((address_space(3))) u32*)(void*)l, 16, 0, 0);
}

// ---------------- convert f32 -> bf16 hi + lo residual ----------------
__global__ __launch_bounds__(256) void cvt_split(const float* __restrict__ in,
                                                 ushort* __restrict__ hi,
                                                 ushort* __restrict__ lo, int n) {
    int i = (blockIdx.x * 256 + threadIdx.x) * 4;
    if (i < n) {
        float4 v = *(const float4*)(in + i);
        ushort4 h, l;
        float* pv = (float*)&v;
        ushort* ph = (ushort*)&h;
        ushort* pl = (ushort*)&l;
#pragma unroll
        for (int j = 0; j < 4; ++j) {
            ushort hh = f2bf(pv[j]);
            ph[j] = hh;
            pl[j] = f2bf(pv[j] - bf2f(hh));
        }
        *(ushort4*)(hi + i) = h;
        *(ushort4*)(lo + i) = l;
    }
}

// ---------------- transpose W (f32 DxD) -> bf16 W^T hi/lo ----------------
__global__ __launch_bounds__(256) void transposeW_split(
    const float* __restrict__ Wq, const float* __restrict__ Wk,
    ushort* __restrict__ WqTh, ushort* __restrict__ WqTl,
    ushort* __restrict__ WkTh, ushort* __restrict__ WkTl) {
    __shared__ float tile[64][65];
    const float* W = blockIdx.z ? Wk : Wq;
    ushort* WTh = blockIdx.z ? WkTh : WqTh;
    ushort* WTl = blockIdx.z ? WkTl : WqTl;
    int kb = blockIdx.y * 64, nb = blockIdx.x * 64;
    int tid = threadIdx.x;
    int tx = tid & 63, ty = tid >> 6;
#pragma unroll
    for (int i = 0; i < 16; ++i) {
        int kl = ty * 16 + i;
        tile[kl][tx] = W[(size_t)(kb + kl) * DD + nb + tx];
    }
    __syncthreads();
#pragma unroll
    for (int i = 0; i < 16; ++i) {
        int nl = ty * 16 + i;
        float v = tile[tx][nl];
        ushort hh = f2bf(v);
        size_t idx = (size_t)(nb + nl) * DD + kb + tx;
        WTh[idx] = hh;
        WTl[idx] = f2bf(v - bf2f(hh));
    }
}

// ---------------- pack mask to bits ----------------
__global__ __launch_bounds__(256) void pack_mask(const int* __restrict__ mask,
                                                 u64* __restrict__ bits, int nwords) {
    int gw = (int)((blockIdx.x * 256 + threadIdx.x) >> 6);
    int lane = threadIdx.x & 63;
    if (gw < nwords) {
        int v = mask[(size_t)gw * 64 + lane];
        u64 m = __ballot(v != 0);
        if (lane == 0) bits[gw] = m;
    }
}

// ---------------- split-precision projection GEMM ----------------
// Computes C = A @ B^T in ~fp32 precision via hi/lo bf16 split:
// virtual K' = 3*1024; k-section 0: Ah*Bh, 1: Ah*Bl, 2: Al*Bh.
// A row stride = DD (1024). Bt: N x DD row-major (hi/lo).
// MODE 0: bias + write bf16 hi/lo C and bf16 C*wcomb[(row>>6)&15]
// MODE 1: bias + write bf16 hi/lo C
template <int MODE>
__global__ __launch_bounds__(256) void gemm_proj(
    const ushort* __restrict__ Ah, const ushort* __restrict__ Al,
    const ushort* __restrict__ Bh, const ushort* __restrict__ Bl,
    const float* __restrict__ bias, const float* __restrict__ wcomb,
    ushort* __restrict__ Chi, ushort* __restrict__ Clo, ushort* __restrict__ Cw) {
    __shared__ __align__(16) ushort As[128 * 64];
    __shared__ __align__(16) ushort Bs[128 * 64];
    const int tn = blockIdx.x, tm = blockIdx.y;
    const int tid = threadIdx.x, lane = tid & 63, w = tid >> 6;
    const int wm = w >> 1, wn = w & 1;
    const int lr = lane >> 4, lc = lane & 15;
    const int N = DD;
    f32x4 acc[4][4];
#pragma unroll
    for (int m = 0; m < 4; ++m)
#pragma unroll
        for (int n = 0; n < 4; ++n) acc[m][n] = (f32x4){0.f, 0.f, 0.f, 0.f};

    for (int kt = 0; kt < 3 * DD; kt += 64) {
        int sec = kt >> 10;
        int kcol = kt & (DD - 1);
        const ushort* Asel = (sec == 2) ? Al : Ah;  // [hi, hi, lo]
        const ushort* Bsel = (sec == 1) ? Bl : Bh;  // [hi, lo, hi]
        __syncthreads();
#pragma unroll
        for (int i = 0; i < 4; ++i) {
            int c = tid + 256 * i;
            int r = c >> 3, col = (c & 7) << 3;
            gload16(Asel + (size_t)(tm * 128 + r) * DD + kcol + col,
                    As + (w * 64 + 256 * i) * 8);
        }
#pragma unroll
        for (int i = 0; i < 4; ++i) {
            int c = tid + 256 * i;
            int r = c >> 3, col = (c & 7) << 3;
            gload16(Bsel + (size_t)(tn * 128 + r) * DD + kcol + col,
                    Bs + (w * 64 + 256 * i) * 8);
        }
        __syncthreads();
        const ushort* Aw = As + (wm * 64) * 64;
        const ushort* Bw = Bs + (wn * 64) * 64;
#pragma unroll
        for (int t = 0; t < 2; ++t) {
            bf16x8 af[4], bfr[4];
#pragma unroll
            for (int m = 0; m < 4; ++m)
                af[m] = *(const bf16x8*)(Aw + (m * 16 + lc) * 64 + t * 32 + lr * 8);
#pragma unroll
            for (int n = 0; n < 4; ++n)
                bfr[n] = *(const bf16x8*)(Bw + (n * 16 + lc) * 64 + t * 32 + lr * 8);
#pragma unroll
            for (int m = 0; m < 4; ++m)
#pragma unroll
                for (int n = 0; n < 4; ++n)
                    acc[m][n] = __builtin_amdgcn_mfma_f32_16x16x32_bf16(af[m], bfr[n], acc[m][n], 0, 0, 0);
        }
    }
#pragma unroll
    for (int m = 0; m < 4; ++m) {
        int grow0 = tm * 128 + wm * 64 + m * 16 + lr * 4;
#pragma unroll
        for (int n = 0; n < 4; ++n) {
            int gcol = tn * 128 + wn * 64 + n * 16 + lc;
#pragma unroll
            for (int r = 0; r < 4; ++r) {
                float v = acc[m][n][r] + bias[gcol];
                int grow = grow0 + r;
                size_t idx = (size_t)grow * N + gcol;
                ushort hh = f2bf(v);
                Chi[idx] = hh;
                Clo[idx] = f2bf(v - bf2f(hh));
                if (MODE == 0) Cw[idx] = f2bf(v * wcomb[(grow >> 6) & 15]);
            }
        }
    }
}

// ---------------- combined-scores GEMM (head-block K) ----------------
// C[b,q,k] = sum_h sum_d qw[b,h,q,d] * kh[b,h,k,d] + bias0
// qw/kh flat (B,H,S,64); per k-step h the 128x64 tile is contiguous.
__global__ __launch_bounds__(256) void gemm_comb(
    const ushort* __restrict__ Aq, const ushort* __restrict__ Bk,
    const float* __restrict__ bias, float* __restrict__ Cf) {
    __shared__ __align__(16) ushort As[128 * 64];
    __shared__ __align__(16) ushort Bs[128 * 64];
    const int bz = blockIdx.z;
    const ushort* Ab = Aq + (size_t)bz * SS * DD;
    const ushort* Bb = Bk + (size_t)bz * SS * DD;
    const int tn = blockIdx.x, tm = blockIdx.y;
    const int tid = threadIdx.x, lane = tid & 63, w = tid >> 6;
    const int wm = w >> 1, wn = w & 1;
    const int lr = lane >> 4, lc = lane & 15;
    f32x4 acc[4][4];
#pragma unroll
    for (int m = 0; m < 4; ++m)
#pragma unroll
        for (int n = 0; n < 4; ++n) acc[m][n] = (f32x4){0.f, 0.f, 0.f, 0.f};

    for (int h = 0; h < HH; ++h) {
        __syncthreads();
        const ushort* Asrc = Ab + (size_t)h * 65536 + tm * 8192;
        const ushort* Bsrc = Bb + (size_t)h * 65536 + tn * 8192;
#pragma unroll
        for (int i = 0; i < 4; ++i) {
            int c = tid + 256 * i;
            gload16(Asrc + (size_t)c * 8, As + (w * 64 + 256 * i) * 8);
        }
#pragma unroll
        for (int i = 0; i < 4; ++i) {
            int c = tid + 256 * i;
            gload16(Bsrc + (size_t)c * 8, Bs + (w * 64 + 256 * i) * 8);
        }
        __syncthreads();
        const ushort* Aw = As + (wm * 64) * 64;
        const ushort* Bw = Bs + (wn * 64) * 64;
#pragma unroll
        for (int t = 0; t < 2; ++t) {
            bf16x8 af[4], bfr[4];
#pragma unroll
            for (int m = 0; m < 4; ++m)
                af[m] = *(const bf16x8*)(Aw + (m * 16 + lc) * 64 + t * 32 + lr * 8);
#pragma unroll
            for (int n = 0; n < 4; ++n)
                bfr[n] = *(const bf16x8*)(Bw + (n * 16 + lc) * 64 + t * 32 + lr * 8);
#pragma unroll
            for (int m = 0; m < 4; ++m)
#pragma unroll
                for (int n = 0; n < 4; ++n)
                    acc[m][n] = __builtin_amdgcn_mfma_f32_16x16x32_bf16(af[m], bfr[n], acc[m][n], 0, 0, 0);
        }
    }
    float b0 = bias[0];
#pragma unroll
    for (int m = 0; m < 4; ++m) {
        int grow0 = tm * 128 + wm * 64 + m * 16 + lr * 4;
#pragma unroll
        for (int n = 0; n < 4; ++n) {
            int gcol = tn * 128 + wn * 64 + n * 16 + lc;
#pragma unroll
            for (int r = 0; r < 4; ++r)
                Cf[(size_t)bz * SS * SS + (size_t)(grow0 + r) * SS + gcol] = acc[m][n][r] + b0;
        }
    }
}

// ---------------- fused flash attention (V = K), split-precision QK^T ----------------
// Per-head Q/K are CONTIGUOUS 1024x64 blocks at (b*HH+h)*SS*64 (reference reshape).
__global__ __launch_bounds__(256) void attn_fused(
    const ushort* __restrict__ qh_, const ushort* __restrict__ ql_,
    const ushort* __restrict__ kh_, const ushort* __restrict__ kl_,
    const u64* __restrict__ mbits, float* __restrict__ ctx) {
    __shared__ __align__(16) ushort Ksh[64 * 72];  // K tile hi (row-major, padded)
    __shared__ __align__(16) ushort Ksl[64 * 72];  // K tile lo
    __shared__ __align__(16) ushort KTs[64 * 72];  // K tile hi transposed (for PV)
    __shared__ __align__(16) ushort Ps[4][16 * 72];
    const int qt = blockIdx.x, h = blockIdx.y, b = blockIdx.z;
    const int tid = threadIdx.x, lane = tid & 63, w = tid >> 6;
    const int lr = lane >> 4, lc = lane & 15;
    const size_t headbase = (size_t)(b * HH + h) * SS * 64;

    bf16x8 qfh[2], qfl[2];
    {
        size_t rowoff = headbase + (size_t)(qt * 64 + w * 16 + lc) * 64;
#pragma unroll
        for (int t = 0; t < 2; ++t) {
            qfh[t] = *(const bf16x8*)(qh_ + rowoff + t * 32 + lr * 8);
            qfl[t] = *(const bf16x8*)(ql_ + rowoff + t * 32 + lr * 8);
        }
    }
    f32x4 acc[4];
#pragma unroll
    for (int dt = 0; dt < 4; ++dt) acc[dt] = (f32x4){0.f, 0.f, 0.f, 0.f};
    float mrow[4] = {-3e38f, -3e38f, -3e38f, -3e38f};
    float lsum[4] = {0.f, 0.f, 0.f, 0.f};

    for (int kt = 0; kt < 16; ++kt) {
        __syncthreads();  // previous tile's PV reads done
        const ushort* khsrc = kh_ + headbase + (size_t)(kt * 64) * 64;
        const ushort* klsrc = kl_ + headbase + (size_t)(kt * 64) * 64;
#pragma unroll
        for (int i = 0; i < 2; ++i) {
            int c = tid + 256 * i;
            int r = c >> 3, col = (c & 7) << 3;
            uint4 vh = *(const uint4*)(khsrc + (size_t)c * 8);
            *(uint4*)&Ksh[r * 72 + col] = vh;
            const ushort* pv = (const ushort*)&vh;
#pragma unroll
            for (int j = 0; j < 8; ++j) KTs[(col + j) * 72 + r] = pv[j];
            uint4 vl = *(const uint4*)(klsrc + (size_t)c * 8);
            *(uint4*)&Ksl[r * 72 + col] = vl;
        }
        __syncthreads();

        // QK^T (split precision): s = qh*kh + qh*kl + ql*kh
        f32x4 sc[4];
#pragma unroll
        for (int nt = 0; nt < 4; ++nt) {
            f32x4 z = (f32x4){0.f, 0.f, 0.f, 0.f};
#pragma unroll
            for (int t = 0; t < 2; ++t) {
                bf16x8 kfh = *(const bf16x8*)(Ksh + (nt * 16 + lc) * 72 + t * 32 + lr * 8);
                bf16x8 kfl = *(const bf16x8*)(Ksl + (nt * 16 + lc) * 72 + t * 32 + lr * 8);
                z = __builtin_amdgcn_mfma_f32_16x16x32_bf16(qfh[t], kfh, z, 0, 0, 0);
                z = __builtin_amdgcn_mfma_f32_16x16x32_bf16(qfh[t], kfl, z, 0, 0, 0);
                z = __builtin_amdgcn_mfma_f32_16x16x32_bf16(qfl[t], kfh, z, 0, 0, 0);
            }
            sc[nt] = z;
        }

        // mask + online softmax (row lr*4+r lives in a contiguous 16-lane group)
#pragma unroll
        for (int r = 0; r < 4; ++r) {
            u64 wbit = mbits[((size_t)b * SS + qt * 64 + w * 16 + lr * 4 + r) * 16 + kt];
            float rmax = -3e38f;
#pragma unroll
            for (int nt = 0; nt < 4; ++nt) {
                int kkloc = nt * 16 + lc;
                float v = sc[nt][r];
                v = ((wbit >> kkloc) & 1ULL) ? v : -3e38f;
                sc[nt][r] = v;
                rmax = fmaxf(rmax, v);
            }
#pragma unroll
            for (int d2 = 1; d2 < 16; d2 <<= 1) rmax = fmaxf(rmax, __shfl_xor(rmax, d2, 64));
            float mnew = fmaxf(mrow[r], rmax);
            float scale = __expf(mrow[r] - mnew);
            float rsum = 0.f;
#pragma unroll
            for (int nt = 0; nt < 4; ++nt) {
                float p = __expf(sc[nt][r] - mnew);
                sc[nt][r] = p;
                rsum += p;
            }
#pragma unroll
            for (int d2 = 1; d2 < 16; d2 <<= 1) rsum += __shfl_xor(rsum, d2, 64);
            lsum[r] = lsum[r] * scale + rsum;
            mrow[r] = mnew;
#pragma unroll
            for (int dt = 0; dt < 4; ++dt) acc[dt][r] *= scale;
        }

        // P -> per-wave LDS (C/D layout -> A-frag layout conversion)
        ushort* P = &Ps[w][0];
#pragma unroll
        for (int nt = 0; nt < 4; ++nt)
#pragma unroll
            for (int r = 0; r < 4; ++r)
                P[(lr * 4 + r) * 72 + nt * 16 + lc] = f2bf(sc[nt][r]);
        asm volatile("s_waitcnt lgkmcnt(0)" ::: "memory");
        __builtin_amdgcn_sched_barrier(0);

        // PV: context += P @ K_tile (V = K hi)
#pragma unroll
        for (int dt = 0; dt < 4; ++dt) {
#pragma unroll
            for (int t = 0; t < 2; ++t) {
                bf16x8 pf = *(const bf16x8*)(P + lc * 72 + t * 32 + lr * 8);
                bf16x8 vf = *(const bf16x8*)(KTs + (dt * 16 + lc) * 72 + t * 32 + lr * 8);
                acc[dt] = __builtin_amdgcn_mfma_f32_16x16x32_bf16(pf, vf, acc[dt], 0, 0, 0);
            }
        }
    }
    // epilogue: output context layout is (B, H, S, DK) contiguous (reference reshape)
#pragma unroll
    for (int r = 0; r < 4; ++r) {
        float l = lsum[r];
        float inv = (l > 0.f) ? 1.f / l : 0.f;
        int q = qt * 64 + w * 16 + lr * 4 + r;
#pragma unroll
        for (int dt = 0; dt < 4; ++dt)
            ctx[(((size_t)(b * HH + h)) * SS + q) * 64 + dt * 16 + lc] = acc[dt][r] * inv;
    }
}

// ---------------- row softmax for probs ----------------
__global__ __launch_bounds__(256) void softmax_rows(float* __restrict__ data) {
    int w = threadIdx.x >> 6, lane = threadIdx.x & 63;
    float* p = data + ((size_t)blockIdx.x * 4 + w) * SS;
    float4 v[4];
    float mx = -3e38f;
#pragma unroll
    for (int i = 0; i < 4; ++i) {
        v[i] = *(const float4*)(p + i * 256 + lane * 4);
        mx = fmaxf(mx, fmaxf(fmaxf(v[i].x, v[i].y), fmaxf(v[i].z, v[i].w)));
    }
#pragma unroll
    for (int d2 = 1; d2 < 64; d2 <<= 1) mx = fmaxf(mx, __shfl_xor(mx, d2, 64));
    float sum = 0.f;
#pragma unroll
    for (int i = 0; i < 4; ++i) {
        v[i].x = __expf(v[i].x - mx);
        v[i].y = __expf(v[i].y - mx);
        v[i].z = __expf(v[i].z - mx);
        v[i].w = __expf(v[i].w - mx);
        sum += v[i].x + v[i].y + v[i].z + v[i].w;
    }
#pragma unroll
    for (int d2 = 1; d2 < 64; d2 <<= 1) sum += __shfl_xor(sum, d2, 64);
    float inv = 1.f / sum;
#pragma unroll
    for (int i = 0; i < 4; ++i) {
        v[i].x *= inv; v[i].y *= inv; v[i].z *= inv; v[i].w *= inv;
        *(float4*)(p + i * 256 + lane * 4) = v[i];
    }
}

extern "C" void kernel_launch(void* const* d_in, const int* in_sizes, int n_in,
                              void* d_out, int out_size, void* d_ws, size_t ws_size,
                              hipStream_t stream) {
    const float* query = (const float*)d_in[0];
    const float* key   = (const float*)d_in[1];
    const int*   mask  = (const int*)d_in[2];
    const float* Wq    = (const float*)d_in[3];
    const float* bq    = (const float*)d_in[4];
    const float* Wk    = (const float*)d_in[5];
    const float* bk    = (const float*)d_in[6];
    const float* wcomb = (const float*)d_in[7];
    const float* bcomb = (const float*)d_in[8];
    float* probs = (float*)d_out;                          // (B,S,S)
    float* ctx   = (float*)d_out + (size_t)BB * SS * SS;   // (B,H,S,DK) flat

    char* ws = (char*)d_ws;
    const size_t MB = 1ull << 20;
    ushort* query_hi = (ushort*)(ws);             // [0,8)
    ushort* query_lo = (ushort*)(ws + 8 * MB);    // [8,16)
    ushort* key_hi   = (ushort*)(ws + 16 * MB);   // [16,24)
    ushort* key_lo   = (ushort*)(ws + 24 * MB);   // [24,32)
    ushort* WqTh     = (ushort*)(ws + 32 * MB);   // [32,34)
    ushort* WqTl     = (ushort*)(ws + 34 * MB);   // [34,36)
    ushort* WkTh     = (ushort*)(ws + 36 * MB);   // [36,38)
    ushort* WkTl     = (ushort*)(ws + 38 * MB);   // [38,40)
    ushort* qw_bf    = (ushort*)(ws + 40 * MB);   // [40,48)
    ushort* q_hi     = (ushort*)(ws + 48 * MB);   // [48,56)
    ushort* q_lo     = (ushort*)(ws + 56 * MB);   // [56,64)
    u64*    mbits    = (u64*)(ws + 64 * MB);      // [64,64.5)
    // k outputs reuse the query staging region (dead after q-projection)
    ushort* k_hi     = (ushort*)(ws);             // [0,8)
    ushort* k_lo     = (ushort*)(ws + 8 * MB);    // [8,16)

    int nElem = BB * SS * DD;
    cvt_split<<<4096, 256, 0, stream>>>(query, query_hi, query_lo, nElem);
    cvt_split<<<4096, 256, 0, stream>>>(key, key_hi, key_lo, nElem);
    transposeW_split<<<dim3(16, 16, 2), 256, 0, stream>>>(Wq, Wk, WqTh, WqTl, WkTh, WkTl);
    pack_mask<<<16384, 256, 0, stream>>>(mask, mbits, BB * SS * (SS / 64));

    // q projection first (reads query_*), then k projection (overwrites query_* region)
    gemm_proj<0><<<dim3(8, 32), 256, 0, stream>>>(query_hi, query_lo, WqTh, WqTl,
                                                  bq, wcomb, q_hi, q_lo, qw_bf);
    gemm_proj<1><<<dim3(8, 32), 256, 0, stream>>>(key_hi, key_lo, WkTh, WkTl,
                                                  bk, nullptr, k_hi, k_lo, nullptr);

    attn_fused<<<dim3(16, 16, 4), 256, 0, stream>>>(q_hi, q_lo, k_hi, k_lo, mbits, ctx);

    gemm_comb<<<dim3(8, 8, 4), 256, 0, stream>>>(qw_bf, k_hi, bcomb, probs);
    softmax_rows<<<1024, 256, 0, stream>>>(probs);
    (void)in_sizes; (void)n_in; (void)out_size; (void)ws_size;
}

// Round 4
// 297.295 us; speedup vs baseline: 1.0092x; 1.0092x over previous
//
#include <hip/hip_runtime.h>
#include <hip/hip_bf16.h>

#define BB 4
#define SS 1024
#define DD 1024
#define HH 16

typedef __attribute__((ext_vector_type(8))) short bf16x8;
typedef __attribute__((ext_vector_type(4))) float f32x4;
typedef unsigned int u32;
typedef unsigned long long u64;

__device__ __forceinline__ ushort f2bf(float f) {
    u32 u = __builtin_bit_cast(u32, f);
    u32 r = (u + 0x7fffu + ((u >> 16) & 1u)) >> 16;
    return (ushort)r;
}
__device__ __forceinline__ float bf2f(ushort h) {
    return __builtin_bit_cast(float, (u32)h << 16);
}

__device__ __forceinline__ void gload16(const ushort* g, ushort* l) {
    __builtin_amdgcn_global_load_lds(
        (const __attribute__((address_space(1))) u32*)(const void*)g,
        (__attribute__((address_space(3))) u32*)(void*)l, 16, 0, 0);
}

// ---------------- convert f32 -> bf16 hi + lo residual ----------------
__global__ __launch_bounds__(256) void cvt_split(const float* __restrict__ in,
                                                 ushort* __restrict__ hi,
                                                 ushort* __restrict__ lo, int n) {
    int i = (blockIdx.x * 256 + threadIdx.x) * 4;
    if (i < n) {
        float4 v = *(const float4*)(in + i);
        ushort4 h, l;
        float* pv = (float*)&v;
        ushort* ph = (ushort*)&h;
        ushort* pl = (ushort*)&l;
#pragma unroll
        for (int j = 0; j < 4; ++j) {
            ushort hh = f2bf(pv[j]);
            ph[j] = hh;
            pl[j] = f2bf(pv[j] - bf2f(hh));
        }
        *(ushort4*)(hi + i) = h;
        *(ushort4*)(lo + i) = l;
    }
}

// ---------------- transpose W (f32 DxD) -> bf16 W^T hi/lo ----------------
__global__ __launch_bounds__(256) void transposeW_split(
    const float* __restrict__ Wq, const float* __restrict__ Wk,
    ushort* __restrict__ WqTh, ushort* __restrict__ WqTl,
    ushort* __restrict__ WkTh, ushort* __restrict__ WkTl) {
    __shared__ float tile[64][65];
    const float* W = blockIdx.z ? Wk : Wq;
    ushort* WTh = blockIdx.z ? WkTh : WqTh;
    ushort* WTl = blockIdx.z ? WkTl : WqTl;
    int kb = blockIdx.y * 64, nb = blockIdx.x * 64;
    int tid = threadIdx.x;
    int tx = tid & 63, ty = tid >> 6;
#pragma unroll
    for (int i = 0; i < 16; ++i) {
        int kl = ty * 16 + i;
        tile[kl][tx] = W[(size_t)(kb + kl) * DD + nb + tx];
    }
    __syncthreads();
#pragma unroll
    for (int i = 0; i < 16; ++i) {
        int nl = ty * 16 + i;
        float v = tile[tx][nl];
        ushort hh = f2bf(v);
        size_t idx = (size_t)(nb + nl) * DD + kb + tx;
        WTh[idx] = hh;
        WTl[idx] = f2bf(v - bf2f(hh));
    }
}

// ---------------- pack mask to bits ----------------
__global__ __launch_bounds__(256) void pack_mask(const int* __restrict__ mask,
                                                 u64* __restrict__ bits, int nwords) {
    int gw = (int)((blockIdx.x * 256 + threadIdx.x) >> 6);
    int lane = threadIdx.x & 63;
    if (gw < nwords) {
        int v = mask[(size_t)gw * 64 + lane];
        u64 m = __ballot(v != 0);
        if (lane == 0) bits[gw] = m;
    }
}

// ---------------- transpose k_hi per head-tile into tiled kT ----------------
// in:  kh[blk*4096 + k*64 + d]   (blk = bh*16 + kt; 64 k-rows x 64 dims)
// out: kT[blk*4096 + d*64 + k]
__global__ __launch_bounds__(256) void transposeK(const ushort* __restrict__ kh,
                                                  ushort* __restrict__ kT) {
    __shared__ ushort t[64 * 66];
    int blk = blockIdx.x;
    const ushort* src = kh + (size_t)blk * 4096;
    ushort* dst = kT + (size_t)blk * 4096;
    int tid = threadIdx.x;
#pragma unroll
    for (int i = 0; i < 2; ++i) {
        int c = tid + 256 * i;
        int r = c >> 3, col = (c & 7) << 3;
        uint4 v = *(const uint4*)(src + (size_t)c * 8);
        const uint* pv = (const uint*)&v;
        *(uint*)(t + r * 66 + col + 0) = pv[0];
        *(uint*)(t + r * 66 + col + 2) = pv[1];
        *(uint*)(t + r * 66 + col + 4) = pv[2];
        *(uint*)(t + r * 66 + col + 6) = pv[3];
    }
    __syncthreads();
#pragma unroll
    for (int i = 0; i < 2; ++i) {
        int c = tid + 256 * i;
        int d = c >> 3, k0 = (c & 7) << 3;
        uint4 o;
        ushort* po = (ushort*)&o;
#pragma unroll
        for (int j = 0; j < 8; ++j) po[j] = t[(k0 + j) * 66 + d];
        *(uint4*)(dst + d * 64 + k0) = o;
    }
}

// ---------------- split-precision projection GEMM ----------------
template <int MODE>
__global__ __launch_bounds__(256) void gemm_proj(
    const ushort* __restrict__ Ah, const ushort* __restrict__ Al,
    const ushort* __restrict__ Bh, const ushort* __restrict__ Bl,
    const float* __restrict__ bias, const float* __restrict__ wcomb,
    ushort* __restrict__ Chi, ushort* __restrict__ Clo, ushort* __restrict__ Cw) {
    __shared__ __align__(16) ushort As[128 * 64];
    __shared__ __align__(16) ushort Bs[128 * 64];
    const int tn = blockIdx.x, tm = blockIdx.y;
    const int tid = threadIdx.x, lane = tid & 63, w = tid >> 6;
    const int wm = w >> 1, wn = w & 1;
    const int lr = lane >> 4, lc = lane & 15;
    const int N = DD;
    f32x4 acc[4][4];
#pragma unroll
    for (int m = 0; m < 4; ++m)
#pragma unroll
        for (int n = 0; n < 4; ++n) acc[m][n] = (f32x4){0.f, 0.f, 0.f, 0.f};

    for (int kt = 0; kt < 3 * DD; kt += 64) {
        int sec = kt >> 10;
        int kcol = kt & (DD - 1);
        const ushort* Asel = (sec == 2) ? Al : Ah;  // [hi, hi, lo]
        const ushort* Bsel = (sec == 1) ? Bl : Bh;  // [hi, lo, hi]
        __syncthreads();
#pragma unroll
        for (int i = 0; i < 4; ++i) {
            int c = tid + 256 * i;
            int r = c >> 3, col = (c & 7) << 3;
            gload16(Asel + (size_t)(tm * 128 + r) * DD + kcol + col,
                    As + (w * 64 + 256 * i) * 8);
        }
#pragma unroll
        for (int i = 0; i < 4; ++i) {
            int c = tid + 256 * i;
            int r = c >> 3, col = (c & 7) << 3;
            gload16(Bsel + (size_t)(tn * 128 + r) * DD + kcol + col,
                    Bs + (w * 64 + 256 * i) * 8);
        }
        __syncthreads();
        const ushort* Aw = As + (wm * 64) * 64;
        const ushort* Bw = Bs + (wn * 64) * 64;
#pragma unroll
        for (int t = 0; t < 2; ++t) {
            bf16x8 af[4], bfr[4];
#pragma unroll
            for (int m = 0; m < 4; ++m)
                af[m] = *(const bf16x8*)(Aw + (m * 16 + lc) * 64 + t * 32 + lr * 8);
#pragma unroll
            for (int n = 0; n < 4; ++n)
                bfr[n] = *(const bf16x8*)(Bw + (n * 16 + lc) * 64 + t * 32 + lr * 8);
#pragma unroll
            for (int m = 0; m < 4; ++m)
#pragma unroll
                for (int n = 0; n < 4; ++n)
                    acc[m][n] = __builtin_amdgcn_mfma_f32_16x16x32_bf16(af[m], bfr[n], acc[m][n], 0, 0, 0);
        }
    }
#pragma unroll
    for (int m = 0; m < 4; ++m) {
        int grow0 = tm * 128 + wm * 64 + m * 16 + lr * 4;
#pragma unroll
        for (int n = 0; n < 4; ++n) {
            int gcol = tn * 128 + wn * 64 + n * 16 + lc;
#pragma unroll
            for (int r = 0; r < 4; ++r) {
                float v = acc[m][n][r] + bias[gcol];
                int grow = grow0 + r;
                size_t idx = (size_t)grow * N + gcol;
                ushort hh = f2bf(v);
                Chi[idx] = hh;
                Clo[idx] = f2bf(v - bf2f(hh));
                if (MODE == 0) Cw[idx] = f2bf(v * wcomb[(grow >> 6) & 15]);
            }
        }
    }
}

// ---------------- combined-scores GEMM (head-block K) ----------------
__global__ __launch_bounds__(256) void gemm_comb(
    const ushort* __restrict__ Aq, const ushort* __restrict__ Bk,
    const float* __restrict__ bias, float* __restrict__ Cf) {
    __shared__ __align__(16) ushort As[128 * 64];
    __shared__ __align__(16) ushort Bs[128 * 64];
    const int bz = blockIdx.z;
    const ushort* Ab = Aq + (size_t)bz * SS * DD;
    const ushort* Bb = Bk + (size_t)bz * SS * DD;
    const int tn = blockIdx.x, tm = blockIdx.y;
    const int tid = threadIdx.x, lane = tid & 63, w = tid >> 6;
    const int wm = w >> 1, wn = w & 1;
    const int lr = lane >> 4, lc = lane & 15;
    f32x4 acc[4][4];
#pragma unroll
    for (int m = 0; m < 4; ++m)
#pragma unroll
        for (int n = 0; n < 4; ++n) acc[m][n] = (f32x4){0.f, 0.f, 0.f, 0.f};

    for (int h = 0; h < HH; ++h) {
        __syncthreads();
        const ushort* Asrc = Ab + (size_t)h * 65536 + tm * 8192;
        const ushort* Bsrc = Bb + (size_t)h * 65536 + tn * 8192;
#pragma unroll
        for (int i = 0; i < 4; ++i) {
            int c = tid + 256 * i;
            gload16(Asrc + (size_t)c * 8, As + (w * 64 + 256 * i) * 8);
        }
#pragma unroll
        for (int i = 0; i < 4; ++i) {
            int c = tid + 256 * i;
            gload16(Bsrc + (size_t)c * 8, Bs + (w * 64 + 256 * i) * 8);
        }
        __syncthreads();
        const ushort* Aw = As + (wm * 64) * 64;
        const ushort* Bw = Bs + (wn * 64) * 64;
#pragma unroll
        for (int t = 0; t < 2; ++t) {
            bf16x8 af[4], bfr[4];
#pragma unroll
            for (int m = 0; m < 4; ++m)
                af[m] = *(const bf16x8*)(Aw + (m * 16 + lc) * 64 + t * 32 + lr * 8);
#pragma unroll
            for (int n = 0; n < 4; ++n)
                bfr[n] = *(const bf16x8*)(Bw + (n * 16 + lc) * 64 + t * 32 + lr * 8);
#pragma unroll
            for (int m = 0; m < 4; ++m)
#pragma unroll
                for (int n = 0; n < 4; ++n)
                    acc[m][n] = __builtin_amdgcn_mfma_f32_16x16x32_bf16(af[m], bfr[n], acc[m][n], 0, 0, 0);
        }
    }
    float b0 = bias[0];
#pragma unroll
    for (int m = 0; m < 4; ++m) {
        int grow0 = tm * 128 + wm * 64 + m * 16 + lr * 4;
#pragma unroll
        for (int n = 0; n < 4; ++n) {
            int gcol = tn * 128 + wn * 64 + n * 16 + lc;
#pragma unroll
            for (int r = 0; r < 4; ++r)
                Cf[(size_t)bz * SS * SS + (size_t)(grow0 + r) * SS + gcol] = acc[m][n][r] + b0;
        }
    }
}

// swizzled LDS frag address (ushort units): row rr, 16B-block bi
#define SWZ(rr, bi) (((rr) << 6) + ((((bi) ^ ((rr) & 7))) << 3))

// ---------------- fused flash attention (V = K), split-precision QK^T ----------------
// K tiles staged via global_load_lds with pre-swizzled source; kT pre-transposed.
__global__ __launch_bounds__(256) void attn_fused(
    const ushort* __restrict__ qh_, const ushort* __restrict__ ql_,
    const ushort* __restrict__ kh_, const ushort* __restrict__ kl_,
    const ushort* __restrict__ kT_, const u64* __restrict__ mbits,
    float* __restrict__ ctx) {
    __shared__ __align__(16) ushort Kb[2][3][4096];  // [buf][kh,kl,kT][64x64 swizzled]
    __shared__ __align__(16) ushort Ps[4][16 * 68];
    const int qt = blockIdx.x, h = blockIdx.y, b = blockIdx.z;
    const int tid = threadIdx.x, lane = tid & 63, w = tid >> 6;
    const int lr = lane >> 4, lc = lane & 15;
    const int bh = b * HH + h;
    const size_t headbase = (size_t)bh * (SS * 64);

    // stage one K tile-set (kh, kl, kT) into buf; linear LDS dest, swizzled src
    auto stage = [&](int buf, int kt) {
#pragma unroll
        for (int i = 0; i < 2; ++i) {
            int ch = (w << 1) + i;                    // chunk 0..7 (1024B each)
            int row = (ch << 3) + (lane >> 3);        // 0..63
            int blkk = (lane & 7) ^ ((lane >> 3) & 7);  // swizzled 16B block
            size_t g = ((size_t)bh * 16 + kt) * 4096 + (size_t)row * 64 + blkk * 8;
            gload16(kh_ + g, &Kb[buf][0][ch * 512]);
            gload16(kl_ + g, &Kb[buf][1][ch * 512]);
            gload16(kT_ + g, &Kb[buf][2][ch * 512]);
        }
    };

    bf16x8 qfh[2], qfl[2];
    {
        size_t rowoff = headbase + (size_t)(qt * 64 + w * 16 + lc) * 64;
#pragma unroll
        for (int t = 0; t < 2; ++t) {
            qfh[t] = *(const bf16x8*)(qh_ + rowoff + t * 32 + lr * 8);
            qfl[t] = *(const bf16x8*)(ql_ + rowoff + t * 32 + lr * 8);
        }
    }
    f32x4 acc[4];
#pragma unroll
    for (int dt = 0; dt < 4; ++dt) acc[dt] = (f32x4){0.f, 0.f, 0.f, 0.f};
    float mrow[4] = {-3e38f, -3e38f, -3e38f, -3e38f};
    float lsum[4] = {0.f, 0.f, 0.f, 0.f};

    stage(0, 0);
    __syncthreads();
    int cur = 0;

    for (int kt = 0; kt < 16; ++kt) {
        if (kt < 15) stage(cur ^ 1, kt + 1);  // prefetch next (hidden under compute)

        const ushort* Bh = &Kb[cur][0][0];
        const ushort* Bl = &Kb[cur][1][0];
        const ushort* Vt = &Kb[cur][2][0];

        // QK^T (split precision): s = qh*kh + qh*kl + ql*kh
        f32x4 sc[4];
#pragma unroll
        for (int nt = 0; nt < 4; ++nt) {
            f32x4 z = (f32x4){0.f, 0.f, 0.f, 0.f};
            __builtin_amdgcn_s_setprio(1);
#pragma unroll
            for (int t = 0; t < 2; ++t) {
                bf16x8 kfh = *(const bf16x8*)(Bh + SWZ(nt * 16 + lc, t * 4 + lr));
                bf16x8 kfl = *(const bf16x8*)(Bl + SWZ(nt * 16 + lc, t * 4 + lr));
                z = __builtin_amdgcn_mfma_f32_16x16x32_bf16(qfh[t], kfh, z, 0, 0, 0);
                z = __builtin_amdgcn_mfma_f32_16x16x32_bf16(qfh[t], kfl, z, 0, 0, 0);
                z = __builtin_amdgcn_mfma_f32_16x16x32_bf16(qfl[t], kfh, z, 0, 0, 0);
            }
            __builtin_amdgcn_s_setprio(0);
            sc[nt] = z;
        }

        // mask + online softmax (row lr*4+r lives in a contiguous 16-lane group)
#pragma unroll
        for (int r = 0; r < 4; ++r) {
            u64 wbit = mbits[((size_t)b * SS + qt * 64 + w * 16 + lr * 4 + r) * 16 + kt];
            float rmax = -3e38f;
#pragma unroll
            for (int nt = 0; nt < 4; ++nt) {
                int kkloc = nt * 16 + lc;
                float v = sc[nt][r];
                v = ((wbit >> kkloc) & 1ULL) ? v : -3e38f;
                sc[nt][r] = v;
                rmax = fmaxf(rmax, v);
            }
#pragma unroll
            for (int d2 = 1; d2 < 16; d2 <<= 1) rmax = fmaxf(rmax, __shfl_xor(rmax, d2, 64));
            float mnew = fmaxf(mrow[r], rmax);
            float scale = __expf(mrow[r] - mnew);
            float rsum = 0.f;
#pragma unroll
            for (int nt = 0; nt < 4; ++nt) {
                float p = __expf(sc[nt][r] - mnew);
                sc[nt][r] = p;
                rsum += p;
            }
#pragma unroll
            for (int d2 = 1; d2 < 16; d2 <<= 1) rsum += __shfl_xor(rsum, d2, 64);
            lsum[r] = lsum[r] * scale + rsum;
            mrow[r] = mnew;
#pragma unroll
            for (int dt = 0; dt < 4; ++dt) acc[dt][r] *= scale;
        }

        // P -> per-wave LDS (C/D layout -> A-frag layout), pitch 68 (conflict-free writes)
        ushort* P = &Ps[w][0];
#pragma unroll
        for (int nt = 0; nt < 4; ++nt)
#pragma unroll
            for (int r = 0; r < 4; ++r)
                P[(lr * 4 + r) * 68 + nt * 16 + lc] = f2bf(sc[nt][r]);
        asm volatile("s_waitcnt lgkmcnt(0)" ::: "memory");
        __builtin_amdgcn_sched_barrier(0);

        bf16x8 pf[2];
#pragma unroll
        for (int t = 0; t < 2; ++t)
            pf[t] = *(const bf16x8*)(P + lc * 68 + t * 32 + lr * 8);

        // PV: context += P @ K_tile (V = K hi, from pre-transposed kT)
        __builtin_amdgcn_s_setprio(1);
#pragma unroll
        for (int dt = 0; dt < 4; ++dt) {
#pragma unroll
            for (int t = 0; t < 2; ++t) {
                bf16x8 vf = *(const bf16x8*)(Vt + SWZ(dt * 16 + lc, t * 4 + lr));
                acc[dt] = __builtin_amdgcn_mfma_f32_16x16x32_bf16(pf[t], vf, acc[dt], 0, 0, 0);
            }
        }
        __builtin_amdgcn_s_setprio(0);

        if (kt < 15) __syncthreads();  // drains vmcnt (stage) + syncs buffers
        cur ^= 1;
    }
    // epilogue: output context layout is (B, H, S, DK) contiguous (reference reshape)
#pragma unroll
    for (int r = 0; r < 4; ++r) {
        float l = lsum[r];
        float inv = (l > 0.f) ? 1.f / l : 0.f;
        int q = qt * 64 + w * 16 + lr * 4 + r;
#pragma unroll
        for (int dt = 0; dt < 4; ++dt)
            ctx[(((size_t)bh) * SS + q) * 64 + dt * 16 + lc] = acc[dt][r] * inv;
    }
}

// ---------------- row softmax for probs ----------------
__global__ __launch_bounds__(256) void softmax_rows(float* __restrict__ data) {
    int w = threadIdx.x >> 6, lane = threadIdx.x & 63;
    float* p = data + ((size_t)blockIdx.x * 4 + w) * SS;
    float4 v[4];
    float mx = -3e38f;
#pragma unroll
    for (int i = 0; i < 4; ++i) {
        v[i] = *(const float4*)(p + i * 256 + lane * 4);
        mx = fmaxf(mx, fmaxf(fmaxf(v[i].x, v[i].y), fmaxf(v[i].z, v[i].w)));
    }
#pragma unroll
    for (int d2 = 1; d2 < 64; d2 <<= 1) mx = fmaxf(mx, __shfl_xor(mx, d2, 64));
    float sum = 0.f;
#pragma unroll
    for (int i = 0; i < 4; ++i) {
        v[i].x = __expf(v[i].x - mx);
        v[i].y = __expf(v[i].y - mx);
        v[i].z = __expf(v[i].z - mx);
        v[i].w = __expf(v[i].w - mx);
        sum += v[i].x + v[i].y + v[i].z + v[i].w;
    }
#pragma unroll
    for (int d2 = 1; d2 < 64; d2 <<= 1) sum += __shfl_xor(sum, d2, 64);
    float inv = 1.f / sum;
#pragma unroll
    for (int i = 0; i < 4; ++i) {
        v[i].x *= inv; v[i].y *= inv; v[i].z *= inv; v[i].w *= inv;
        *(float4*)(p + i * 256 + lane * 4) = v[i];
    }
}

extern "C" void kernel_launch(void* const* d_in, const int* in_sizes, int n_in,
                              void* d_out, int out_size, void* d_ws, size_t ws_size,
                              hipStream_t stream) {
    const float* query = (const float*)d_in[0];
    const float* key   = (const float*)d_in[1];
    const int*   mask  = (const int*)d_in[2];
    const float* Wq    = (const float*)d_in[3];
    const float* bq    = (const float*)d_in[4];
    const float* Wk    = (const float*)d_in[5];
    const float* bk    = (const float*)d_in[6];
    const float* wcomb = (const float*)d_in[7];
    const float* bcomb = (const float*)d_in[8];
    float* probs = (float*)d_out;                          // (B,S,S)
    float* ctx   = (float*)d_out + (size_t)BB * SS * SS;   // (B,H,S,DK) flat

    char* ws = (char*)d_ws;
    const size_t MB = 1ull << 20;
    ushort* query_hi = (ushort*)(ws);             // [0,8)
    ushort* query_lo = (ushort*)(ws + 8 * MB);    // [8,16)
    ushort* key_hi   = (ushort*)(ws + 16 * MB);   // [16,24)
    ushort* key_lo   = (ushort*)(ws + 24 * MB);   // [24,32)
    ushort* WqTh     = (ushort*)(ws + 32 * MB);   // [32,34)
    ushort* WqTl     = (ushort*)(ws + 34 * MB);   // [34,36)
    ushort* WkTh     = (ushort*)(ws + 36 * MB);   // [36,38)
    ushort* WkTl     = (ushort*)(ws + 38 * MB);   // [38,40)
    ushort* qw_bf    = (ushort*)(ws + 40 * MB);   // [40,48)
    ushort* q_hi     = (ushort*)(ws + 48 * MB);   // [48,56)
    ushort* q_lo     = (ushort*)(ws + 56 * MB);   // [56,64)
    u64*    mbits    = (u64*)(ws + 64 * MB);      // [64,64.5)
    ushort* kT       = (ushort*)(ws + 65 * MB);   // [65,73)
    // k outputs reuse the query staging region (dead after q-projection)
    ushort* k_hi     = (ushort*)(ws);             // [0,8)
    ushort* k_lo     = (ushort*)(ws + 8 * MB);    // [8,16)

    int nElem = BB * SS * DD;
    cvt_split<<<4096, 256, 0, stream>>>(query, query_hi, query_lo, nElem);
    cvt_split<<<4096, 256, 0, stream>>>(key, key_hi, key_lo, nElem);
    transposeW_split<<<dim3(16, 16, 2), 256, 0, stream>>>(Wq, Wk, WqTh, WqTl, WkTh, WkTl);
    pack_mask<<<16384, 256, 0, stream>>>(mask, mbits, BB * SS * (SS / 64));

    // q projection first (reads query_*), then k projection (overwrites query_* region)
    gemm_proj<0><<<dim3(8, 32), 256, 0, stream>>>(query_hi, query_lo, WqTh, WqTl,
                                                  bq, wcomb, q_hi, q_lo, qw_bf);
    gemm_proj<1><<<dim3(8, 32), 256, 0, stream>>>(key_hi, key_lo, WkTh, WkTl,
                                                  bk, nullptr, k_hi, k_lo, nullptr);

    transposeK<<<1024, 256, 0, stream>>>(k_hi, kT);

    attn_fused<<<dim3(16, 16, 4), 256, 0, stream>>>(q_hi, q_lo, k_hi, k_lo, kT, mbits, ctx);

    gemm_comb<<<dim3(8, 8, 4), 256, 0, stream>>>(qw_bf, k_hi, bcomb, probs);
    softmax_rows<<<1024, 256, 0, stream>>>(probs);
    (void)in_sizes; (void)n_in; (void)out_size; (void)ws_size;
}